// Round 5
// baseline (542.720 us; speedup 1.0000x reference)
//
#include <hip/hip_runtime.h>
#include <math.h>

#define BB 512
#define TT 1024
#define LL 48
#define PF 8            // emission prefetch depth (loads in flight)
#define TSTRIDE 49      // padded T row stride: bank = (17*i + j) % 32, conflict-free

__device__ __forceinline__ float readlane_f(float v, int lane) {
    return __int_as_float(__builtin_amdgcn_readlane(__float_as_int(v), lane));
}

// One DPP butterfly/broadcast stage of a full-wave max (register-file cross-lane,
// ~VALU latency; NOT ds_bpermute and NOT an LDS round-trip).
template <int CTRL>
__device__ __forceinline__ float dppmax(float x) {
    int y = __builtin_amdgcn_update_dpp(__float_as_int(x), __float_as_int(x),
                                        CTRL, 0xF, 0xF, false);
    return fmaxf(x, __int_as_float(y));
}

// Wave max of z, then lowest-lane index of bitwise equality (== reference
// first-max argmax; lanes holding -INF never match). ~13 VALU + 1 SALU.
__device__ __forceinline__ int wave_argmax(float z) {
    float r = z;
    r = dppmax<0xB1>(r);    // quad_perm [1,0,3,2] : xor 1
    r = dppmax<0x4E>(r);    // quad_perm [2,3,0,1] : xor 2
    r = dppmax<0x141>(r);   // row_half_mirror     : xor 4
    r = dppmax<0x140>(r);   // row_mirror          : xor 8
    r = dppmax<0x142>(r);   // row_bcast15         : 16->31, 47->63 merge
    r = dppmax<0x143>(r);   // row_bcast31         : lane 63 = full-wave max
    float m = readlane_f(r, 63);
    unsigned long long eq = __ballot(z == m);
    return (int)__builtin_ctzll(eq);     // s_ff1: lowest index wins ties
}

// Forward pass stores VALUES ONLY; backtrack recomputes the one argmax per
// step actually on the path (bitwise-identical floats, ffs tie-break).
//
// waves_per_eu(1,1): wall time here is single-chain serial latency (512
// independent chains on 1024 SIMDs) — occupancy is worthless, registers are
// everything. Without this the allocator targeted 8 waves/EU (VGPR=48,
// round 4) and re-loaded tc[48] from memory EVERY step: ~530 stall cyc/step.
__global__ __launch_bounds__(64)
__attribute__((amdgpu_waves_per_eu(1, 1)))
void viterbi_kernel(
    const float* __restrict__ emissions,   // [B,T,L]
    const float* __restrict__ transitions, // [L,L]
    const float* __restrict__ start_tr,    // [L]
    const float* __restrict__ end_tr,      // [L]
    int* __restrict__ out,                 // [B,T] int32
    float* __restrict__ vws)               // workspace: [B][T][L] viterbi rows
{
    __shared__ float tlds[LL * TSTRIDE];   // T padded for backtrack column reads

    const int b  = blockIdx.x;
    const int j  = threadIdx.x;
    const int jc = (j < LL) ? j : (LL - 1);       // lanes 48-63 mirror lane 47

    // Transition column jc in registers (forward); T into LDS (backtrack).
    float tc[LL];
#pragma unroll
    for (int i = 0; i < LL; ++i) {
        tc[i] = transitions[i * LL + jc];
        tlds[i * TSTRIDE + jc] = tc[i];    // lanes 48-63 dup-write col 47: same value
    }
    // Pin tc in VGPRs: forbid rematerialization-as-load (round-4 failure mode).
#pragma unroll
    for (int i = 0; i < LL; ++i)
        asm volatile("" : "+v"(tc[i]));

    const float* em = emissions + (size_t)b * TT * LL;
    float* vr_g = vws + (size_t)b * TT * LL;      // this chain's [T][48] rows

    float v = start_tr[jc] + em[jc];
    vr_g[jc] = v;                                  // row 0 (dup lanes: same value)

    // 8-deep emission prefetch ring.
    float er[PF];
#pragma unroll
    for (int k = 0; k < PF; ++k)
        er[k] = em[(size_t)(1 + k) * LL + jc];

    // One value-only Viterbi step (serial chain: v -> v).
    auto step = [&](int t, float e) {
        float s[LL];
#pragma unroll
        for (int i = 0; i < LL; ++i)
            s[i] = readlane_f(v, i) + tc[i];

        float m1[16];
#pragma unroll
        for (int k = 0; k < 16; ++k)
            m1[k] = fmaxf(fmaxf(s[3 * k], s[3 * k + 1]), s[3 * k + 2]);
        float m2[6];
#pragma unroll
        for (int k = 0; k < 5; ++k)
            m2[k] = fmaxf(fmaxf(m1[3 * k], m1[3 * k + 1]), m1[3 * k + 2]);
        m2[5] = m1[15];
        float best = fmaxf(fmaxf(fmaxf(m2[0], m2[1]), m2[2]),
                           fmaxf(fmaxf(m2[3], m2[4]), m2[5]));

        v = best + e;                              // chain continues here
        vr_g[(size_t)t * LL + jc] = v;             // off-chain coalesced store
    };

    // Main loop: blocks of 8 with compile-time-constant ring indices.
    int tb = 1;
    for (; tb + PF <= TT; tb += PF) {
#pragma unroll
        for (int k = 0; k < PF; ++k) {
            int t = tb + k;
            float e = er[k];
            int tn = t + PF; if (tn > TT - 1) tn = TT - 1;   // scalar clamp
            er[k] = em[(size_t)tn * LL + jc];      // refill: 8 loads in flight
            step(t, e);
        }
    }
#pragma unroll
    for (int k = 0; k < PF - 1; ++k) {
        int t = tb + k;
        if (t < TT) step(t, er[k]);
    }

    // ---- final tag: wave-parallel argmax of v + end ----
    float vf = (j < LL) ? (v + end_tr[jc]) : -INFINITY;
    int tag = wave_argmax(vf);                     // uniform (SGPR) tag

    int* ob = out + (size_t)b * TT;
    if (j == 0) ob[TT - 1] = tag;

    // ---- backtrack: recompute argmax only along the path ----
    // tag_p = argmax_i( v_p[i] + T[i][tag_{p+1}] ), p = T-2 .. 0.
    // v-rows prefetched 32 at a time (addresses tag-independent).
    for (int hi = TT - 2; hi >= 0; hi -= 32) {
        int lo = hi - 31; if (lo < 0) lo = 0;
        int n = hi - lo + 1;                       // wave-uniform

        float vr[32];
#pragma unroll
        for (int k = 31; k >= 0; --k)              // issue order == consume order
            if (k < n) vr[k] = vr_g[(size_t)(lo + k) * LL + jc];

        int outv = 0;
#pragma unroll
        for (int k = 31; k >= 0; --k) {
            if (k < n) {
                // lane i reads T[i][tag]: dwords (17*i + tag) % 32 -> no conflicts
                float tcol = tlds[jc * TSTRIDE + tag];
                float z = (j < LL) ? (vr[k] + tcol) : -INFINITY;
                tag = wave_argmax(z);              // chain: ds_read+add+dpp+ballot
                outv = (j == k) ? tag : outv;      // tag is SGPR -> one cndmask
            }
        }
        if (j < n) ob[lo + j] = outv;
    }
}

extern "C" void kernel_launch(void* const* d_in, const int* in_sizes, int n_in,
                              void* d_out, int out_size, void* d_ws, size_t ws_size,
                              hipStream_t stream) {
    const float* emissions   = (const float*)d_in[0];
    // d_in[1] = mask — unused by the reference decode body
    const float* transitions = (const float*)d_in[2];
    const float* start_tr    = (const float*)d_in[3];
    const float* end_tr      = (const float*)d_in[4];
    int* out = (int*)d_out;

    // Viterbi rows: B * T * L * 4 = 100,663,296 B in the provided workspace.
    float* vws = (float*)d_ws;

    viterbi_kernel<<<dim3(BB), dim3(64), 0, stream>>>(
        emissions, transitions, start_tr, end_tr, out, vws);
}

// Round 6
// 533.788 us; speedup vs baseline: 1.0167x; 1.0167x over previous
//
#include <hip/hip_runtime.h>
#include <math.h>

#define BB 512
#define TT 1024
#define LL 48
#define PF 8            // steps per phase (ring half-depth)
#define TSTRIDE 49      // padded T row stride: bank = (17*i + j) % 32, conflict-free

__device__ __forceinline__ float readlane_f(float v, int lane) {
    return __int_as_float(__builtin_amdgcn_readlane(__float_as_int(v), lane));
}

// One DPP butterfly/broadcast stage of a full-wave max (register-file cross-lane).
template <int CTRL>
__device__ __forceinline__ float dppmax(float x) {
    int y = __builtin_amdgcn_update_dpp(__float_as_int(x), __float_as_int(x),
                                        CTRL, 0xF, 0xF, false);
    return fmaxf(x, __int_as_float(y));
}

// Wave max of z, then lowest-lane index of bitwise equality (== reference
// first-max argmax; lanes holding -INF never match). ~13 VALU + 1 SALU.
__device__ __forceinline__ int wave_argmax(float z) {
    float r = z;
    r = dppmax<0xB1>(r);    // quad_perm [1,0,3,2] : xor 1
    r = dppmax<0x4E>(r);    // quad_perm [2,3,0,1] : xor 2
    r = dppmax<0x141>(r);   // row_half_mirror     : xor 4
    r = dppmax<0x140>(r);   // row_mirror          : xor 8
    r = dppmax<0x142>(r);   // row_bcast15         : 16->31, 47->63 merge
    r = dppmax<0x143>(r);   // row_bcast31         : lane 63 = full-wave max
    float m = readlane_f(r, 63);
    unsigned long long eq = __ballot(z == m);
    return (int)__builtin_ctzll(eq);     // s_ff1: lowest index wins ties
}

// Forward pass stores VALUES ONLY; backtrack recomputes the one argmax per
// step on the path (bitwise-identical floats, ffs tie-break).
//
// Phase-split schedule: the 8-step bodies are PURE VALU (no loads, no
// stores); all vmem (8 v-row stores + 8 emission refills) is clustered in a
// flush block between phases. Rounds 0/4/5 all showed a ~550-660 cyc/step
// stall invariant to register residency and issue count — hypothesis: the
// compiler's per-step vmcnt waits put memory latency on the serial chain.
// Here no s_waitcnt can land inside a step body (consume distance 16-24
// steps, one wait per 8 steps, off-chain).
__global__ __launch_bounds__(64)
__attribute__((amdgpu_waves_per_eu(1, 1)))
void viterbi_kernel(
    const float* __restrict__ emissions,   // [B,T,L]
    const float* __restrict__ transitions, // [L,L]
    const float* __restrict__ start_tr,    // [L]
    const float* __restrict__ end_tr,      // [L]
    int* __restrict__ out,                 // [B,T] int32
    float* __restrict__ vws)               // workspace: [B][T][L] viterbi rows
{
    __shared__ float tlds[LL * TSTRIDE];   // T padded for backtrack column reads

    const int b  = blockIdx.x;
    const int j  = threadIdx.x;
    const int jc = (j < LL) ? j : (LL - 1);       // lanes 48-63 mirror lane 47

    // Transition column jc in registers (forward); T into LDS (backtrack).
    float tc[LL];
#pragma unroll
    for (int i = 0; i < LL; ++i) {
        tc[i] = transitions[i * LL + jc];
        tlds[i * TSTRIDE + jc] = tc[i];    // lanes 48-63 dup-write col 47: same value
    }
#pragma unroll
    for (int i = 0; i < LL; ++i)
        asm volatile("" : "+v"(tc[i]));    // pin: forbid remat-as-load (round-4 mode)

    const float* em = emissions + (size_t)b * TT * LL;
    float* vr_g = vws + (size_t)b * TT * LL;      // this chain's [T][48] rows

    float v = start_tr[jc] + em[jc];
    vr_g[jc] = v;                                  // row 0 (dup lanes: same value)

    // Double-buffered emission rings: erA = times tb..tb+7, erB = tb+8..tb+15.
    float erA[PF], erB[PF];
#pragma unroll
    for (int k = 0; k < PF; ++k) {
        erA[k] = em[(size_t)(1 + k) * LL + jc];
        erB[k] = em[(size_t)(1 + PF + k) * LL + jc];
    }

    // One value-only Viterbi step (serial chain: v -> v). PURE VALU.
    auto step_v = [&](float e) {
        float s[LL];
#pragma unroll
        for (int i = 0; i < LL; ++i)
            s[i] = readlane_f(v, i) + tc[i];

        float m1[16];
#pragma unroll
        for (int k = 0; k < 16; ++k)
            m1[k] = fmaxf(fmaxf(s[3 * k], s[3 * k + 1]), s[3 * k + 2]);
        float m2[6];
#pragma unroll
        for (int k = 0; k < 5; ++k)
            m2[k] = fmaxf(fmaxf(m1[3 * k], m1[3 * k + 1]), m1[3 * k + 2]);
        m2[5] = m1[15];
        float best = fmaxf(fmaxf(fmaxf(m2[0], m2[1]), m2[2]),
                           fmaxf(fmaxf(m2[3], m2[4]), m2[5]));
        v = best + e;                              // chain continues here
    };

    float vsave[PF];                               // parked v-rows of one phase

    // Main loop: 16 timesteps per iteration, two {compute8, flush8} phases.
    int tb = 1;
    for (; tb + 2 * PF <= TT; tb += 2 * PF) {
        // ---- phase A: steps tb..tb+7 (pure VALU) ----
#pragma unroll
        for (int k = 0; k < PF; ++k) { step_v(erA[k]); vsave[k] = v; }
        // ---- flush A: park rows to global, refill erA with tb+16..tb+23 ----
#pragma unroll
        for (int k = 0; k < PF; ++k) {
            vr_g[(size_t)(tb + k) * LL + jc] = vsave[k];
            int tn = tb + 2 * PF + k; if (tn > TT - 1) tn = TT - 1;
            erA[k] = em[(size_t)tn * LL + jc];
        }
        // ---- phase B: steps tb+8..tb+15 (pure VALU) ----
#pragma unroll
        for (int k = 0; k < PF; ++k) { step_v(erB[k]); vsave[k] = v; }
        // ---- flush B: park rows, refill erB with tb+24..tb+31 ----
#pragma unroll
        for (int k = 0; k < PF; ++k) {
            vr_g[(size_t)(tb + PF + k) * LL + jc] = vsave[k];
            int tn = tb + 3 * PF + k; if (tn > TT - 1) tn = TT - 1;
            erB[k] = em[(size_t)tn * LL + jc];
        }
    }
    // Tail: tb = 1009, steps 1009..1023 (15): 8 from erA, 7 from erB.
#pragma unroll
    for (int k = 0; k < PF; ++k) {
        int t = tb + k;
        if (t < TT) { step_v(erA[k]); vr_g[(size_t)t * LL + jc] = v; }
    }
#pragma unroll
    for (int k = 0; k < PF; ++k) {
        int t = tb + PF + k;
        if (t < TT) { step_v(erB[k]); vr_g[(size_t)t * LL + jc] = v; }
    }

    // ---- final tag: wave-parallel argmax of v + end ----
    float vf = (j < LL) ? (v + end_tr[jc]) : -INFINITY;
    int tag = wave_argmax(vf);                     // uniform (SGPR) tag

    int* ob = out + (size_t)b * TT;
    if (j == 0) ob[TT - 1] = tag;

    // ---- backtrack: recompute argmax only along the path ----
    // tag_p = argmax_i( v_p[i] + T[i][tag_{p+1}] ), p = T-2 .. 0.
    for (int hi = TT - 2; hi >= 0; hi -= 32) {
        int lo = hi - 31; if (lo < 0) lo = 0;
        int n = hi - lo + 1;                       // wave-uniform

        float vr[32];
#pragma unroll
        for (int k = 31; k >= 0; --k)              // issue order == consume order
            if (k < n) vr[k] = vr_g[(size_t)(lo + k) * LL + jc];

        int outv = 0;
#pragma unroll
        for (int k = 31; k >= 0; --k) {
            if (k < n) {
                // lane i reads T[i][tag]: dwords (17*i + tag) % 32 -> no conflicts
                float tcol = tlds[jc * TSTRIDE + tag];
                float z = (j < LL) ? (vr[k] + tcol) : -INFINITY;
                tag = wave_argmax(z);              // chain: ds_read+add+dpp+ballot
                outv = (j == k) ? tag : outv;      // tag is SGPR -> one cndmask
            }
        }
        if (j < n) ob[lo + j] = outv;
    }
}

extern "C" void kernel_launch(void* const* d_in, const int* in_sizes, int n_in,
                              void* d_out, int out_size, void* d_ws, size_t ws_size,
                              hipStream_t stream) {
    const float* emissions   = (const float*)d_in[0];
    // d_in[1] = mask — unused by the reference decode body
    const float* transitions = (const float*)d_in[2];
    const float* start_tr    = (const float*)d_in[3];
    const float* end_tr      = (const float*)d_in[4];
    int* out = (int*)d_out;

    // Viterbi rows: B * T * L * 4 = 100,663,296 B in the provided workspace.
    float* vws = (float*)d_ws;

    viterbi_kernel<<<dim3(BB), dim3(64), 0, stream>>>(
        emissions, transitions, start_tr, end_tr, out, vws);
}